// Round 3
// baseline (284.281 us; speedup 1.0000x reference)
//
#include <hip/hip_runtime.h>
#include <math.h>

typedef __attribute__((ext_vector_type(4))) float f32x4;
typedef __attribute__((ext_vector_type(8))) short short8;

#define BM   32
#define KB   128
#define NC   32      // 4096 / 128
#define KDIM 4096
#define NTOK 16384
#define KP   8       // LDS pad (shorts)
#define DELTA 4e-4f

__device__ inline unsigned short f2bf(float x) {
  unsigned u = __float_as_uint(x);
  u += 0x7fffu + ((u >> 16) & 1u);
  return (unsigned short)(u >> 16);
}
__device__ inline float bf2f(unsigned short h) {
  return __uint_as_float(((unsigned)h) << 16);
}
// returns packed {hi, lo} bf16 split of x
__device__ inline unsigned split2(float x) {
  unsigned short h = f2bf(x);
  unsigned short l = f2bf(x - bf2f(h));
  return (unsigned)h | ((unsigned)l << 16);
}

__global__ __launch_bounds__(512, 4) void router_kernel(
    const float* __restrict__ H, const float* __restrict__ W,
    float* __restrict__ out)
{
  __shared__ __align__(16) unsigned short Ahi[BM][KB + KP];
  __shared__ __align__(16) unsigned short Alo[BM][KB + KP];
  __shared__ __align__(16) unsigned short Whi[64][KB + KP];
  __shared__ __align__(16) unsigned short Wlo[64][KB + KP];
  __shared__ float  LG[BM][72];
  __shared__ double dlog[64];
  __shared__ int    refList[BM];
  __shared__ int    refCnt;

  const int tid  = threadIdx.x;
  const int lane = tid & 63;
  const int wave = tid >> 6;   // 0..7
  const int mh   = wave >> 2;  // token-half 0..1
  const int nf   = wave & 3;   // expert-frag 0..3
  const int tb   = blockIdx.x * BM;

  if (tid == 0) refCnt = 0;

  // --- A staging map: 16 threads/row, 8 floats each
  const int srow = tid >> 4;
  const int skq  = (tid & 15) * 8;
  const float* hptr = H + (size_t)(tb + srow) * KDIM + skq;

  // --- W staging map: 8 threads/expert-row, 16 floats each
  const int wrow = tid >> 3;
  const int wkq  = (tid & 7) * 16;
  const float* wptr = W + (size_t)wrow * KDIM + wkq;

  // --- MFMA fragment map (16x16x32): row/col = lane&15, kgroup = lane>>4
  const int kg8 = (lane >> 4) * 8;
  const unsigned short* Ah = &Ahi[mh * 16 + (lane & 15)][kg8];
  const unsigned short* Al = &Alo[mh * 16 + (lane & 15)][kg8];
  const unsigned short* Bh = &Whi[nf * 16 + (lane & 15)][kg8];
  const unsigned short* Bl = &Wlo[nf * 16 + (lane & 15)][kg8];

  f32x4 acc = {0.f, 0.f, 0.f, 0.f};

  // prefetch chunk 0
  f32x4 a0 = reinterpret_cast<const f32x4*>(hptr)[0];
  f32x4 a1 = reinterpret_cast<const f32x4*>(hptr)[1];
  f32x4 w0 = reinterpret_cast<const f32x4*>(wptr)[0];
  f32x4 w1 = reinterpret_cast<const f32x4*>(wptr)[1];
  f32x4 w2 = reinterpret_cast<const f32x4*>(wptr)[2];
  f32x4 w3 = reinterpret_cast<const f32x4*>(wptr)[3];

  for (int c = 0; c < NC; ++c) {
    __syncthreads();  // previous chunk's readers done
    // convert + stage A
    {
      short8 h8, l8;
      #pragma unroll
      for (int j = 0; j < 4; ++j) {
        unsigned p0 = split2(a0[j]);
        unsigned p1 = split2(a1[j]);
        h8[j]     = (short)(p0 & 0xffffu);
        l8[j]     = (short)(p0 >> 16);
        h8[4 + j] = (short)(p1 & 0xffffu);
        l8[4 + j] = (short)(p1 >> 16);
      }
      *reinterpret_cast<short8*>(&Ahi[srow][skq]) = h8;
      *reinterpret_cast<short8*>(&Alo[srow][skq]) = l8;
    }
    // convert + stage W chunk (shared by all waves)
    {
      short8 h8, l8;
      #pragma unroll
      for (int j = 0; j < 4; ++j) {
        unsigned p0 = split2(w0[j]);
        unsigned p1 = split2(w1[j]);
        h8[j]     = (short)(p0 & 0xffffu);
        l8[j]     = (short)(p0 >> 16);
        h8[4 + j] = (short)(p1 & 0xffffu);
        l8[4 + j] = (short)(p1 >> 16);
      }
      *reinterpret_cast<short8*>(&Whi[wrow][wkq]) = h8;
      *reinterpret_cast<short8*>(&Wlo[wrow][wkq]) = l8;
      #pragma unroll
      for (int j = 0; j < 4; ++j) {
        unsigned p0 = split2(w2[j]);
        unsigned p1 = split2(w3[j]);
        h8[j]     = (short)(p0 & 0xffffu);
        l8[j]     = (short)(p0 >> 16);
        h8[4 + j] = (short)(p1 & 0xffffu);
        l8[4 + j] = (short)(p1 >> 16);
      }
      *reinterpret_cast<short8*>(&Whi[wrow][wkq + 8]) = h8;
      *reinterpret_cast<short8*>(&Wlo[wrow][wkq + 8]) = l8;
    }
    // prefetch next chunk into registers (overlaps compute)
    if (c + 1 < NC) {
      const float* hp = hptr + (size_t)(c + 1) * KB;
      const float* wp = wptr + (size_t)(c + 1) * KB;
      a0 = reinterpret_cast<const f32x4*>(hp)[0];
      a1 = reinterpret_cast<const f32x4*>(hp)[1];
      w0 = reinterpret_cast<const f32x4*>(wp)[0];
      w1 = reinterpret_cast<const f32x4*>(wp)[1];
      w2 = reinterpret_cast<const f32x4*>(wp)[2];
      w3 = reinterpret_cast<const f32x4*>(wp)[3];
    }
    __syncthreads();  // stores visible

    #pragma unroll
    for (int kf = 0; kf < 4; ++kf) {
      const short8 ah = *reinterpret_cast<const short8*>(Ah + kf * 32);
      const short8 al = *reinterpret_cast<const short8*>(Al + kf * 32);
      const short8 bh = *reinterpret_cast<const short8*>(Bh + kf * 32);
      const short8 bl = *reinterpret_cast<const short8*>(Bl + kf * 32);
      acc = __builtin_amdgcn_mfma_f32_16x16x32_bf16(ah, bh, acc, 0, 0, 0);
      acc = __builtin_amdgcn_mfma_f32_16x16x32_bf16(ah, bl, acc, 0, 0, 0);
      acc = __builtin_amdgcn_mfma_f32_16x16x32_bf16(al, bh, acc, 0, 0, 0);
    }
  }

  // --- epilogue: C fragments -> LDS logits[token][expert]
  {
    int col   = nf * 16 + (lane & 15);
    int rbase = mh * 16 + (lane >> 4) * 4;
    #pragma unroll
    for (int r = 0; r < 4; ++r)
      LG[rbase + r][col] = acc[r];
  }
  __syncthreads();

  // --- top-8 per token (lane = expert); flag near-ties for f64 refine
  for (int t4 = 0; t4 < 4; ++t4) {
    int t = wave * 4 + t4;
    float x = LG[t][lane];
    float m = x;
    #pragma unroll
    for (int off = 32; off > 0; off >>= 1)
      m = fmaxf(m, __shfl_xor(m, off, 64));
    float v = x;
    float selV = 0.f, sum = 0.f, prev = 0.f, gapmin = 1e30f;
    int   selI = 0;
    #pragma unroll
    for (int j = 0; j < 9; ++j) {     // top-9: 8 outputs + rank-9 for the gap
      float bv = v;
      int   bi = lane;
      #pragma unroll
      for (int off = 32; off > 0; off >>= 1) {
        float ov = __shfl_xor(bv, off, 64);
        int   oi = __shfl_xor(bi, off, 64);
        if (ov > bv || (ov == bv && oi < bi)) { bv = ov; bi = oi; }
      }
      if (j > 0) gapmin = fminf(gapmin, prev - bv);
      prev = bv;
      if (j < 8) {
        float e = __expf(bv - m);
        sum += e;
        if (lane == j) { selV = e; selI = bi; }
      }
      if (lane == bi) v = -INFINITY;
    }
    bool flag = (gapmin < DELTA);
    if (flag && lane == 0) {
      int p = atomicAdd(&refCnt, 1);
      refList[p] = t;
    }
    if (!flag && lane < 8) {
      int tg = tb + t;
      out[(size_t)tg * 8 + lane] = selV / sum;
      out[(size_t)NTOK * 8 + (size_t)tg * 8 + lane] = (float)selI;
    }
  }
  __syncthreads();

  // --- f64 refine for flagged tokens (rare): exact ranking
  const int nref = refCnt;
  const int re  = tid >> 3;   // expert 0..63
  const int rs  = tid & 7;    // k-slice 0..7
  for (int i = 0; i < nref; ++i) {
    const int t = refList[i];
    const float* hrow = H + (size_t)(tb + t) * KDIM;
    const float* wrw  = W + (size_t)re * KDIM;
    double accd = 0.0;
    for (int k0 = 0; k0 < KDIM; k0 += 32) {
      f32x4 hv = *reinterpret_cast<const f32x4*>(hrow + k0 + rs * 4);
      f32x4 wv = *reinterpret_cast<const f32x4*>(wrw  + k0 + rs * 4);
      #pragma unroll
      for (int j = 0; j < 4; ++j)
        accd = fma((double)hv[j], (double)wv[j], accd);
    }
    accd += __shfl_xor(accd, 1, 64);
    accd += __shfl_xor(accd, 2, 64);
    accd += __shfl_xor(accd, 4, 64);
    if (rs == 0) dlog[re] = accd;
    __syncthreads();
    if (tid < 64) {   // wave 0: exact f64 top-8
      double x = dlog[tid];
      double m = x;
      #pragma unroll
      for (int off = 32; off > 0; off >>= 1)
        m = fmax(m, __shfl_xor(m, off, 64));
      double v = x, sum = 0.0, selV = 0.0;
      int selI = 0;
      #pragma unroll
      for (int j = 0; j < 8; ++j) {
        double bv = v;
        int    bi = tid;
        #pragma unroll
        for (int off = 32; off > 0; off >>= 1) {
          double ov = __shfl_xor(bv, off, 64);
          int    oi = __shfl_xor(bi, off, 64);
          if (ov > bv || (ov == bv && oi < bi)) { bv = ov; bi = oi; }
        }
        double e = exp(bv - m);
        sum += e;
        if (tid == j) { selV = e; selI = bi; }
        if (tid == bi) v = -1e300;
      }
      if (tid < 8) {
        int tg = tb + t;
        out[(size_t)tg * 8 + tid] = (float)(selV / sum);
        out[(size_t)NTOK * 8 + (size_t)tg * 8 + tid] = (float)selI;
      }
    }
    __syncthreads();
  }
}

extern "C" void kernel_launch(void* const* d_in, const int* in_sizes, int n_in,
                              void* d_out, int out_size, void* d_ws, size_t ws_size,
                              hipStream_t stream) {
  const float* H = (const float*)d_in[0];   // [4,4096,4096] f32
  const float* W = (const float*)d_in[1];   // [64,4096] f32
  float* out = (float*)d_out;               // weights [16384*8] then idx [16384*8]
  router_kernel<<<NTOK / BM, 512, 0, stream>>>(H, W, out);
}

// Round 4
// 201.183 us; speedup vs baseline: 1.4131x; 1.4131x over previous
//
#include <hip/hip_runtime.h>
#include <math.h>

typedef __attribute__((ext_vector_type(4))) float f32x4;
typedef __attribute__((ext_vector_type(8))) short short8;
typedef __attribute__((ext_vector_type(4))) unsigned int u32x4;

#define KDIM  4096
#define NTOK  16384
#define BT    64           // tokens per block (2 token-groups x 32)
#define KHALF 1024         // K per kh-slice (4 slices)
#define CH    (KHALF/32)   // 32 chunks of K=32
#define DELTA 1.2e-4f

union S8U { u32x4 u; short8 s; };
__device__ inline short8 as_s8(u32x4 v) { S8U t; t.u = v; return t.s; }

// split (x0,x1) into hi+lo bf16 planes (round-half-up), packed pairwise
__device__ inline void splitpair(float x0, float x1, unsigned& hp, unsigned& lp) {
  unsigned u0 = __float_as_uint(x0) + 0x8000u;
  unsigned u1 = __float_as_uint(x1) + 0x8000u;
  hp = (u0 >> 16) | (u1 & 0xffff0000u);
  float h0 = __uint_as_float(u0 & 0xffff0000u);
  float h1 = __uint_as_float(u1 & 0xffff0000u);
  float l0 = x0 - h0;
  float l1 = x1 - h1;
  unsigned v0 = __float_as_uint(l0) + 0x8000u;
  unsigned v1 = __float_as_uint(l1) + 0x8000u;
  lp = (v0 >> 16) | (v1 & 0xffff0000u);
}

#define LOADA(st, c) do { \
  apf[st][0] = *(const f32x4*)(Arow + (size_t)(c) * 32); \
  apf[st][1] = *(const f32x4*)(Arow + (size_t)(c) * 32 + 4); \
  apf[st][2] = *(const f32x4*)(Arow + 16 * KDIM + (size_t)(c) * 32); \
  apf[st][3] = *(const f32x4*)(Arow + 16 * KDIM + (size_t)(c) * 32 + 4); \
} while (0)

#define LOADW(st, c) do { \
  _Pragma("unroll") \
  for (int nf_ = 0; nf_ < 4; ++nf_) { \
    wpf[st][nf_ * 2]     = *(const f32x4*)(Wrow + (size_t)nf_ * 16 * KDIM + (size_t)(c) * 32); \
    wpf[st][nf_ * 2 + 1] = *(const f32x4*)(Wrow + (size_t)nf_ * 16 * KDIM + (size_t)(c) * 32 + 4); \
  } \
} while (0)

#define STEP(J) do { \
  const int c_ = cc + (J); \
  u32x4 ahv[2], alv[2], bhv[4], blv[4]; \
  _Pragma("unroll") for (int rt = 0; rt < 2; ++rt) \
    _Pragma("unroll") for (int q = 0; q < 4; ++q) { \
      float x0 = apf[(J) & 3][rt * 2 + (q >> 1)][(q & 1) * 2]; \
      float x1 = apf[(J) & 3][rt * 2 + (q >> 1)][(q & 1) * 2 + 1]; \
      unsigned hp, lp; splitpair(x0, x1, hp, lp); \
      ahv[rt][q] = hp; alv[rt][q] = lp; } \
  _Pragma("unroll") for (int nf = 0; nf < 4; ++nf) \
    _Pragma("unroll") for (int q = 0; q < 4; ++q) { \
      float x0 = wpf[(J) & 1][nf * 2 + (q >> 1)][(q & 1) * 2]; \
      float x1 = wpf[(J) & 1][nf * 2 + (q >> 1)][(q & 1) * 2 + 1]; \
      unsigned hp, lp; splitpair(x0, x1, hp, lp); \
      bhv[nf][q] = hp; blv[nf][q] = lp; } \
  if (c_ + 4 < CH) LOADA((J) & 3, c_ + 4); \
  if (c_ + 2 < CH) LOADW((J) & 1, c_ + 2); \
  _Pragma("unroll") for (int rt = 0; rt < 2; ++rt) \
    _Pragma("unroll") for (int nf = 0; nf < 4; ++nf) { \
      acc[rt][nf] = __builtin_amdgcn_mfma_f32_16x16x32_bf16(as_s8(ahv[rt]), as_s8(bhv[nf]), acc[rt][nf], 0, 0, 0); \
      acc[rt][nf] = __builtin_amdgcn_mfma_f32_16x16x32_bf16(as_s8(ahv[rt]), as_s8(blv[nf]), acc[rt][nf], 0, 0, 0); \
      acc[rt][nf] = __builtin_amdgcn_mfma_f32_16x16x32_bf16(as_s8(alv[rt]), as_s8(bhv[nf]), acc[rt][nf], 0, 0, 0); \
    } \
} while (0)

__global__ __launch_bounds__(512, 2) void router_kernel(
    const float* __restrict__ H, const float* __restrict__ W,
    float* __restrict__ out)
{
  __shared__ float  LG[BT][68];
  __shared__ double dlog[64];
  __shared__ int    refList[BT];
  __shared__ int    refCnt;

  const int tid  = threadIdx.x;
  const int lane = tid & 63;
  const int wv   = tid >> 6;   // 0..7
  const int tg   = wv >> 2;    // token-group 0..1 (32 tokens each)
  const int kh   = wv & 3;     // K-slice 0..3
  const int l15  = lane & 15;
  const int kg8  = (lane >> 4) * 8;
  const int tb   = blockIdx.x * BT;

  if (tid == 0) refCnt = 0;

  const float* Arow = H + (size_t)(tb + tg * 32 + l15) * KDIM + (size_t)kh * KHALF + kg8;
  const float* Wrow = W + (size_t)l15 * KDIM + (size_t)kh * KHALF + kg8;

  f32x4 acc[2][4] = {};
  f32x4 apf[4][4];   // A prefetch: 4 stages x (2 row-tiles x 8 floats)
  f32x4 wpf[2][8];   // W prefetch: 2 stages x (4 expert-frags x 8 floats)

  LOADA(0, 0); LOADA(1, 1); LOADA(2, 2); LOADA(3, 3);
  LOADW(0, 0); LOADW(1, 1);

  #pragma unroll 1
  for (int cc = 0; cc < CH; cc += 4) {
    STEP(0); STEP(1); STEP(2); STEP(3);
  }

  // --- K-split reduce into LDS, deterministic sequential order kh=0,1,2,3
  #pragma unroll 1
  for (int kk = 0; kk < 4; ++kk) {
    if (kh == kk) {
      #pragma unroll
      for (int rt = 0; rt < 2; ++rt)
        #pragma unroll
        for (int nf = 0; nf < 4; ++nf)
          #pragma unroll
          for (int r = 0; r < 4; ++r) {
            int tt  = tg * 32 + rt * 16 + (lane >> 4) * 4 + r;
            int col = nf * 16 + l15;
            if (kk == 0) LG[tt][col]  = acc[rt][nf][r];
            else         LG[tt][col] += acc[rt][nf][r];
          }
    }
    __syncthreads();
  }

  // --- top-8 per token (lane = expert); flag near-ties for f64 refine
  for (int t8 = 0; t8 < 8; ++t8) {
    int t = wv * 8 + t8;
    float x = LG[t][lane];
    float m = x;
    #pragma unroll
    for (int off = 32; off > 0; off >>= 1)
      m = fmaxf(m, __shfl_xor(m, off, 64));
    float v = x;
    float selV = 0.f, sum = 0.f, prev = 0.f, gapmin = 1e30f;
    int   selI = 0;
    #pragma unroll
    for (int j = 0; j < 9; ++j) {   // top-9: 8 outputs + rank-9 gap
      float bv = v;
      int   bi = lane;
      #pragma unroll
      for (int off = 32; off > 0; off >>= 1) {
        float ov = __shfl_xor(bv, off, 64);
        int   oi = __shfl_xor(bi, off, 64);
        if (ov > bv || (ov == bv && oi < bi)) { bv = ov; bi = oi; }
      }
      if (j > 0) gapmin = fminf(gapmin, prev - bv);
      prev = bv;
      if (j < 8) {
        float e = __expf(bv - m);
        sum += e;
        if (lane == j) { selV = e; selI = bi; }
      }
      if (lane == bi) v = -INFINITY;
    }
    bool flag = (gapmin < DELTA);
    if (flag && lane == 0) {
      int p = atomicAdd(&refCnt, 1);
      refList[p] = t;
    }
    if (!flag && lane < 8) {
      int tgl = tb + t;
      out[(size_t)tgl * 8 + lane] = selV / sum;
      out[(size_t)NTOK * 8 + (size_t)tgl * 8 + lane] = (float)selI;
    }
  }
  __syncthreads();

  // --- f64 refine for flagged tokens (rare): exact ranking
  const int nref = refCnt;
  const int re = tid >> 3;   // expert 0..63
  const int rs = tid & 7;    // k-slice 0..7
  for (int i = 0; i < nref; ++i) {
    const int t = refList[i];
    const float* hrow = H + (size_t)(tb + t) * KDIM;
    const float* wrw  = W + (size_t)re * KDIM;
    double accd = 0.0;
    for (int k0 = 0; k0 < KDIM; k0 += 32) {
      f32x4 hv = *reinterpret_cast<const f32x4*>(hrow + k0 + rs * 4);
      f32x4 wvv = *reinterpret_cast<const f32x4*>(wrw + k0 + rs * 4);
      #pragma unroll
      for (int j = 0; j < 4; ++j)
        accd = fma((double)hv[j], (double)wvv[j], accd);
    }
    accd += __shfl_xor(accd, 1, 64);
    accd += __shfl_xor(accd, 2, 64);
    accd += __shfl_xor(accd, 4, 64);
    if (rs == 0) dlog[re] = accd;
    __syncthreads();
    if (tid < 64) {   // wave 0: exact f64 top-8
      double x = dlog[tid];
      double m = x;
      #pragma unroll
      for (int off = 32; off > 0; off >>= 1)
        m = fmax(m, __shfl_xor(m, off, 64));
      double v = x, sum = 0.0, selV = 0.0;
      int selI = 0;
      #pragma unroll
      for (int j = 0; j < 8; ++j) {
        double bv = v;
        int    bi = tid;
        #pragma unroll
        for (int off = 32; off > 0; off >>= 1) {
          double ov = __shfl_xor(bv, off, 64);
          int    oi = __shfl_xor(bi, off, 64);
          if (ov > bv || (ov == bv && oi < bi)) { bv = ov; bi = oi; }
        }
        double e = exp(bv - m);
        sum += e;
        if (tid == j) { selV = e; selI = bi; }
        if (tid == bi) v = -1e300;
      }
      if (tid < 8) {
        int tgl = tb + t;
        out[(size_t)tgl * 8 + tid] = (float)(selV / sum);
        out[(size_t)NTOK * 8 + (size_t)tgl * 8 + tid] = (float)selI;
      }
    }
    __syncthreads();
  }
}

extern "C" void kernel_launch(void* const* d_in, const int* in_sizes, int n_in,
                              void* d_out, int out_size, void* d_ws, size_t ws_size,
                              hipStream_t stream) {
  const float* H = (const float*)d_in[0];   // [4,4096,4096] f32
  const float* W = (const float*)d_in[1];   // [64,4096] f32
  float* out = (float*)d_out;               // weights [16384*8] then idx [16384*8]
  router_kernel<<<NTOK / BT, 512, 0, stream>>>(H, W, out);
}